// Round 7
// baseline (186.006 us; speedup 1.0000x reference)
//
#include <hip/hip_runtime.h>

// VectorQuantizer R11: input (16,64,64,64) f32 channel-first, codebook (1024,64) f32.
// out = [quantized (16,64,64,64) f32 | indices (16,64,64) as f32].
//
// SINGLE fused kernel. R6's proven 32x32x16 main loop (45.3us, best of 5 structural
// variants R6-R10), with prep/CH/workspace deleted:
//  - A fragments computed ON THE FLY from codebook: lane gathers its 32 f32 of
//    row (q*8+t)*32+(lane&31) (lanes l, l+32 share 64B lines; codebook 256KB is
//    L2-resident), splits hi/lo f16 in-register. A = +C exact to 2^-22.
//  - the -2 is folded into B at staging: B = f16(-2x). err = |c . delta(2x)|,
//    same envelope as R8/R10's validated 2-pass (EPS=0.04, absmax 0 twice).
//  - esq per tile in-register: partial = sum c^2 over own 32 cols +
//    shfl_xor(partial,32) -> exact-f32 e, split hi/lo f16 into the ones-trick
//    ae chunk (pairs with B5 = ones at k=0,1). Proven R6 mechanism.
//  - wave-parallel exact rescan (proven R10, absmax 0 on real flagged tokens),
//    now self-contained: minimizes exact-f32 sum (c-x)^2 (same argmin as
//    esq-2dot, constant shift), ascending-k tie-break.
// Rationale: scan resisted 4 structural attacks (R7 occupancy, R8 fewer MFMA,
// R9/R10 chain restructure: all null or worse; it is latency-bound at ~22%
// pipes). The unattacked 15us is prep + second launch. This kernel deletes it.
// Tracking: value+slot separate regs -> exact gap test; ties (gap 0) flagged.

typedef _Float16 v8h  __attribute__((ext_vector_type(8)));
typedef float    v16f __attribute__((ext_vector_type(16)));

constexpr int   D         = 64;
constexpr int   K         = 1024;
constexpr int   HW        = 4096;
constexpr int   DHW       = D * HW;
constexpr int   OUT_ELEMS = 16 * DHW;
constexpr float EPS       = 0.04f;

__global__ __launch_bounds__(256, 3) void vq_fused(
    const float* __restrict__ input,
    const float* __restrict__ codebook,
    float* __restrict__ out)
{
    // u.bf (B staging, dead after fragment loads) unions u.q (epilogue gather).
    __shared__ union {
        _Float16 bf[2][4][64][8];      // [ct][kc][lane][8], 8 KB
        float    q[64][65];            // winner rows for epilogue, 16.6 KB
    } u;
    __shared__ float s_pv[4][64];
    __shared__ float s_p2[4][64];
    __shared__ int   s_pk[4][64];
    __shared__ int   s_idx[64];
    __shared__ int   s_list[64];
    __shared__ int   s_cnt;
    __shared__ float s_xf[4][64];              // per-wave rescan token (f32)

    const int tid  = threadIdx.x;
    const int lane = tid & 63;
    const int q    = __builtin_amdgcn_readfirstlane(tid >> 6);  // K-quarter / wave
    const int lh   = lane >> 5;
    const int tok0 = blockIdx.x * 64;
    const int b    = tok0 >> 12;
    const int hwb  = tok0 & 4095;

    if (tid == 0) s_cnt = 0;

    // ---- cooperative B staging: f16(-2x) (the -2 lives in B; A stays +C) ----
    {
        const float* xb = input + (size_t)b * DHW + hwb;
        #pragma unroll
        for (int pass = 0; pass < 4; ++pass) {
            const int d   = pass * 16 + (tid >> 4);
            const int tk4 = (tid & 15) * 4;
            const float4 v = *(const float4*)(xb + (size_t)d * HW + tk4);
            const float vv[4] = {v.x, v.y, v.z, v.w};
            #pragma unroll
            for (int uu = 0; uu < 4; ++uu) {
                const int tk = tk4 + uu;
                u.bf[tk >> 5][d >> 4][((d >> 3) & 1) * 32 + (tk & 31)][d & 7] =
                    (_Float16)(-2.0f * vv[uu]);
            }
        }
    }
    __syncthreads();

    // ---- B fragments from LDS (proven R6 layout) ----
    v8h bh[2][4];
    #pragma unroll
    for (int ct = 0; ct < 2; ++ct)
        #pragma unroll
        for (int kc = 0; kc < 4; ++kc)
            bh[ct][kc] = *(const v8h*)&u.bf[ct][kc][lane][0];

    // B5: ones at k=0,1 (pairs with esq chunk)
    v8h b5;
    #pragma unroll
    for (int j = 0; j < 8; ++j) b5[j] = (_Float16)0.0f;
    if (lh == 0) { b5[0] = (_Float16)1.0f; b5[1] = (_Float16)1.0f; }

    v16f Z = {0,0,0,0,0,0,0,0,0,0,0,0,0,0,0,0};
    const float INF = __builtin_huge_valf();
    float bv0 = INF, b20 = INF, bv1 = INF, b21 = INF;
    int   sl0 = 0, sl1 = 0;

    // ---- hot loop: 8 tiles x (A on-the-fly + esq + 18 MFMA + track) ----
    #pragma unroll 1
    for (int t = 0; t < 8; ++t) {
        const int row = (q * 8 + t) * 32 + (lane & 31);
        const float* crow = codebook + (size_t)row * D + lh * 8;

        // gather own 32 f32 of the row (cols lh*8+{0..7} + kc*16), split hi/lo
        v8h ah[4], al[4];
        float partial = 0.f;
        #pragma unroll
        for (int kc = 0; kc < 4; ++kc) {
            const float4 c0 = *(const float4*)(crow + kc * 16);
            const float4 c1 = *(const float4*)(crow + kc * 16 + 4);
            const float cv[8] = {c0.x, c0.y, c0.z, c0.w, c1.x, c1.y, c1.z, c1.w};
            v8h hi, lo;
            #pragma unroll
            for (int j = 0; j < 8; ++j) {
                const float v  = cv[j];
                const _Float16 vh = (_Float16)v;
                hi[j] = vh;
                lo[j] = (_Float16)(v - (float)vh);
                partial = fmaf(v, v, partial);
            }
            ah[kc] = hi;
            al[kc] = lo;
        }
        // exact-f32 esq for this lane's row (both halves via lane^32)
        const float e = partial + __shfl_xor(partial, 32, 64);
        v8h ae;
        #pragma unroll
        for (int j = 0; j < 8; ++j) ae[j] = (_Float16)0.0f;
        if (lh == 0) {
            const _Float16 eh = (_Float16)e;
            ae[0] = eh;
            ae[1] = (_Float16)(e - (float)eh);
        }

        v16f acc0 = __builtin_amdgcn_mfma_f32_32x32x16_f16(ae, b5, Z, 0, 0, 0);
        v16f acc1 = __builtin_amdgcn_mfma_f32_32x32x16_f16(ae, b5, Z, 0, 0, 0);
        #pragma unroll
        for (int kc = 0; kc < 4; ++kc) {
            acc0 = __builtin_amdgcn_mfma_f32_32x32x16_f16(ah[kc], bh[0][kc], acc0, 0, 0, 0);
            acc1 = __builtin_amdgcn_mfma_f32_32x32x16_f16(ah[kc], bh[1][kc], acc1, 0, 0, 0);
        }
        #pragma unroll
        for (int kc = 0; kc < 4; ++kc) {
            acc0 = __builtin_amdgcn_mfma_f32_32x32x16_f16(al[kc], bh[0][kc], acc0, 0, 0, 0);
            acc1 = __builtin_amdgcn_mfma_f32_32x32x16_f16(al[kc], bh[1][kc], acc1, 0, 0, 0);
        }

        // track top-2 value + slot (value & slot separate: exact gap test)
        #pragma unroll
        for (int r = 0; r < 16; ++r) {
            const int slot = (t << 4) | r;
            const float s0 = acc0[r];
            b20 = __builtin_amdgcn_fmed3f(s0, bv0, b20);
            if (s0 < bv0) { bv0 = s0; sl0 = slot; }
            const float s1 = acc1[r];
            b21 = __builtin_amdgcn_fmed3f(s1, bv1, b21);
            if (s1 < bv1) { bv1 = s1; sl1 = slot; }
        }
    }

    // ---- cross-half-row merge (lane <-> lane^32), decode cw ----
    #pragma unroll
    for (int ct = 0; ct < 2; ++ct) {
        const float bv = ct ? bv1 : bv0;
        const float b2 = ct ? b21 : b20;
        const int   sl = ct ? sl1 : sl0;
        const float obv = __shfl_xor(bv, 32, 64);
        const float ob2 = __shfl_xor(b2, 32, 64);
        const int   osl = __shfl_xor(sl, 32, 64);
        const bool  oth = obv < bv;            // strict: ties keep own; exact ties flagged
        const float B1  = oth ? obv : bv;
        const float B2  = fminf(fmaxf(bv, obv), fminf(b2, ob2));
        const int   wsl = oth ? osl : sl;
        const int   wlh = oth ? (lh ^ 1) : lh;
        const int   r   = wsl & 15;
        const int   tt  = wsl >> 4;
        const int   cw  = (q * 8 + tt) * 32 + (r & 3) + 8 * (r >> 2) + 4 * wlh;
        if (lane < 32) {
            s_pv[q][ct * 32 + lane] = B1;
            s_p2[q][ct * 32 + lane] = B2;
            s_pk[q][ct * 32 + lane] = cw;
        }
    }
    __syncthreads();

    // ---- merge 4 quarters per token; flag near-ties into list ----
    if (tid < 64) {
        float B1 = INF, B2 = INF; int CW = 0;
        #pragma unroll
        for (int qq = 0; qq < 4; ++qq) {
            const float pv = s_pv[qq][tid];
            const float p2 = s_p2[qq][tid];
            const int   pk = s_pk[qq][tid];
            if (pv < B1) { B2 = fminf(B1, p2); B1 = pv; CW = pk; }
            else         { B2 = fminf(B2, pv); }
        }
        s_idx[tid] = CW;
        if (B2 - B1 < EPS) {
            const int p = atomicAdd(&s_cnt, 1);
            s_list[p] = tid;
        }
    }
    __syncthreads();

    // ---- exact fp32 rescan, WAVE-parallel, self-contained: min sum (c-x)^2 ----
    // (same argmin as esq-2dot: constant ||x||^2 shift; ascending-k strict <)
    {
        const int cnt = s_cnt;
        for (int ii = q; ii < cnt; ii += 4) {
            const int tl = s_list[ii];
            s_xf[q][lane] = input[(size_t)b * DHW + (size_t)lane * HW + (hwb + tl)];
            float ss[16];
            #pragma unroll
            for (int i = 0; i < 16; ++i) ss[i] = 0.f;
            #pragma unroll 4
            for (int dc = 0; dc < 16; ++dc) {
                const float4 x4 = *(const float4*)&s_xf[q][dc * 4];
                #pragma unroll
                for (int i = 0; i < 16; ++i) {
                    const int k = i * 64 + lane;
                    const float4 c4 = *(const float4*)(codebook + (size_t)k * D + dc * 4);
                    const float d0 = c4.x - x4.x;
                    const float d1 = c4.y - x4.y;
                    const float d2 = c4.z - x4.z;
                    const float d3 = c4.w - x4.w;
                    ss[i] = fmaf(d0, d0, ss[i]);
                    ss[i] = fmaf(d1, d1, ss[i]);
                    ss[i] = fmaf(d2, d2, ss[i]);
                    ss[i] = fmaf(d3, d3, ss[i]);
                }
            }
            float bestv = INF; int bestk = 0x7fffffff;
            #pragma unroll
            for (int i = 0; i < 16; ++i) {            // ascending k per lane: strict <
                const int k = i * 64 + lane;
                if (ss[i] < bestv) { bestv = ss[i]; bestk = k; }
            }
            #pragma unroll
            for (int off = 1; off < 64; off <<= 1) {  // lexicographic (val, k) reduce
                const float ov = __shfl_xor(bestv, off, 64);
                const int   ok = __shfl_xor(bestk, off, 64);
                if (ov < bestv || (ov == bestv && ok < bestk)) { bestv = ov; bestk = ok; }
            }
            if (lane == 0) s_idx[tl] = bestk;          // distinct tl per wave: no race
        }
    }
    __syncthreads();

    // ---- epilogue: gather winner rows to LDS (u.q overlays dead u.bf) ----
    {
        const int rs  = tid >> 2;
        const int c   = tid & 3;
        const int idx = s_idx[rs];
        const float4* src = (const float4*)(codebook + (size_t)idx * D + c * 16);
        #pragma unroll
        for (int j = 0; j < 4; ++j) {
            const float4 v = src[j];
            float* dst = &u.q[rs][c * 16 + j * 4];
            dst[0] = v.x; dst[1] = v.y; dst[2] = v.z; dst[3] = v.w;
        }
    }
    __syncthreads();
    {
        float* ob = out + (size_t)b * DHW + hwb;
        #pragma unroll
        for (int pass = 0; pass < 4; ++pass) {
            const int d   = pass * 16 + (tid >> 4);
            const int tk4 = (tid & 15) * 4;
            float4 v;
            v.x = u.q[tk4 + 0][d];
            v.y = u.q[tk4 + 1][d];
            v.z = u.q[tk4 + 2][d];
            v.w = u.q[tk4 + 3][d];
            *(float4*)(ob + (size_t)d * HW + tk4) = v;
        }
        if (tid < 64) out[OUT_ELEMS + tok0 + tid] = (float)s_idx[tid];
    }
}

extern "C" void kernel_launch(void* const* d_in, const int* in_sizes, int n_in,
                              void* d_out, int out_size, void* d_ws, size_t ws_size,
                              hipStream_t stream) {
    const float* input    = (const float*)d_in[0];
    const float* codebook = (const float*)d_in[1];
    float* out            = (float*)d_out;
    (void)d_ws; (void)ws_size;   // workspace unused: no prep kernel, no CH

    vq_fused<<<1024, 256, 0, stream>>>(input, codebook, out);
}

// Round 9
// 105.570 us; speedup vs baseline: 1.7619x; 1.7619x over previous
//
#include <hip/hip_runtime.h>

// VectorQuantizer R12 = R6 revert: input (16,64,64,64) f32, codebook (1024,64) f32.
// out = [quantized (16,64,64,64) f32 | indices (16,64,64) as f32].
//
// Best measured configuration (105.3us total, scan 45.3us). Structural attacks
// R7 (occupancy 4/CU: null), R8 (fewer MFMA + wide EPS: rescan tail), R9 (4-chain
// 128-token: spilled), R10 (16x16 short chains: 2x worse), R11 (single-kernel
// fusion: scratch blowup) all regressed -- scan is latency-bound at ~22% MFMA +
// ~22% VALU with no saturated pipe; this operating point is the empirical optimum.
//
// A = codebook, B = tokens, mfma_f32_32x32x16_f16, SPLIT-F16 3-pass:
//   v = v_hi + v_lo (f16 each); dot = hi*hi + hi*lo + lo*hi  (lo*lo ~2^-22 dropped)
//   -> score error ~3e-5. esq folded via hi/lo 5th-chunk vs ones-B.
// Tracking: value+slot in separate regs -> exact gap test, EPS = 1e-3 ->
// ~1e-4 flag rate. Rescan: block-cooperative exact fp32, ascending-k strict-min
// tie-break; ties (gap 0) always flagged.

typedef _Float16 v8h  __attribute__((ext_vector_type(8)));
typedef float    v16f __attribute__((ext_vector_type(16)));

constexpr int   D         = 64;
constexpr int   K         = 1024;
constexpr int   HW        = 4096;
constexpr int   DHW       = D * HW;
constexpr int   OUT_ELEMS = 16 * DHW;
constexpr float EPS       = 1e-3f;

// CH: 32 tiles x 9 chunks x 64 lanes x 8 f16 = 288 KB.
// frag f = t*9+kc; CH[f*512 + lane*8 + j]:
//   kc 0-3: hi of -2*C[row = t*32+(lane&31)][k = kc*16+(lane>>5)*8+j]
//   kc 4-7: lo of same
//   kc 8  : lh==0: j0=e_hi, j1=e_lo (pairs with B5 = ones at k=0,1)

__global__ __launch_bounds__(256) void vq_prep(
    const float* __restrict__ cb, _Float16* __restrict__ CH, float* __restrict__ esq)
{
    const int blk = blockIdx.x, tid = threadIdx.x;
    if (blk < 72) {
        const int gid  = blk * 256 + tid;          // [0, 18432)
        const int lane = gid & 63;
        const int fid  = gid >> 6;                 // [0, 288)
        const int t    = fid / 9;
        const int kc   = fid - 9 * t;
        const int l31  = lane & 31;
        const int lh   = lane >> 5;
        const int cw   = t * 32 + l31;
        v8h h;
        if (kc < 8) {
            const int  kk = kc & 3;
            const bool lo = kc >= 4;
            const float* src = cb + cw * D + kk * 16 + lh * 8;
            #pragma unroll
            for (int j = 0; j < 8; ++j) {
                const float v = -2.0f * src[j];
                const _Float16 vh = (_Float16)v;
                h[j] = lo ? (_Float16)(v - (float)vh) : vh;
            }
        } else {
            #pragma unroll
            for (int j = 0; j < 8; ++j) h[j] = (_Float16)0.0f;
            if (lh == 0) {
                const float4* c4 = (const float4*)(cb + cw * D);
                float a0 = 0.f, a1 = 0.f, a2 = 0.f, a3 = 0.f;
                #pragma unroll
                for (int j = 0; j < 16; ++j) {
                    const float4 c = c4[j];
                    a0 = fmaf(c.x, c.x, a0);
                    a1 = fmaf(c.y, c.y, a1);
                    a2 = fmaf(c.z, c.z, a2);
                    a3 = fmaf(c.w, c.w, a3);
                }
                const float e = (a0 + a1) + (a2 + a3);
                const _Float16 ehi = (_Float16)e;
                h[0] = ehi;
                h[1] = (_Float16)(e - (float)ehi);
            }
        }
        *(v8h*)(CH + (size_t)fid * 512 + lane * 8) = h;
    } else {
        const int cw = (blk - 72) * 256 + tid;     // exact f32 e_sq for rescan
        const float4* c4 = (const float4*)(cb + cw * D);
        float a0 = 0.f, a1 = 0.f, a2 = 0.f, a3 = 0.f;
        #pragma unroll
        for (int j = 0; j < 16; ++j) {
            const float4 c = c4[j];
            a0 = fmaf(c.x, c.x, a0);
            a1 = fmaf(c.y, c.y, a1);
            a2 = fmaf(c.z, c.z, a2);
            a3 = fmaf(c.w, c.w, a3);
        }
        esq[cw] = (a0 + a1) + (a2 + a3);
    }
}

__global__ __launch_bounds__(256, 3) void vq_scan(
    const float* __restrict__ input,
    const float* __restrict__ codebook,
    const _Float16* __restrict__ CH,
    const float* __restrict__ esq,
    float* __restrict__ out)
{
    __shared__ _Float16 s_bf[2][2][4][64][8];  // [hi/lo][ct][kc][lane][8], 16 KB
    __shared__ float    s_esq[K];              // exact e_sq (rescan), 4 KB
    __shared__ float    s_pv[4][64];
    __shared__ float    s_p2[4][64];
    __shared__ int      s_pk[4][64];
    __shared__ int      s_idx[64];
    __shared__ int      s_list[64];
    __shared__ int      s_cnt;
    __shared__ float    s_xf[64];              // rescan token (f32)
    __shared__ float    s_redv[4];
    __shared__ int      s_redk[4];
    __shared__ float    s_q[64][65];           // winner rows for epilogue

    const int tid  = threadIdx.x;
    const int lane = tid & 63;
    const int q    = __builtin_amdgcn_readfirstlane(tid >> 6);  // K-quarter
    const int lh   = lane >> 5;
    const int tok0 = blockIdx.x * 64;
    const int b    = tok0 >> 12;
    const int hwb  = tok0 & 4095;

    if (tid == 0) s_cnt = 0;

    // ---- stage exact e_sq ----
    *(float4*)&s_esq[tid * 4] = *(const float4*)&esq[tid * 4];

    // ---- cooperative B staging: hi+lo split ----
    {
        const float* xb = input + (size_t)b * DHW + hwb;
        #pragma unroll
        for (int pass = 0; pass < 4; ++pass) {
            const int d   = pass * 16 + (tid >> 4);
            const int hw4 = (tid & 15) * 4;
            const float4 v = *(const float4*)(xb + (size_t)d * HW + hw4);
            const float vv[4] = {v.x, v.y, v.z, v.w};
            #pragma unroll
            for (int u = 0; u < 4; ++u) {
                const int tk = hw4 + u;
                const float f = vv[u];
                const _Float16 fh = (_Float16)f;
                s_bf[0][tk >> 5][d >> 4][((d >> 3) & 1) * 32 + (tk & 31)][d & 7] = fh;
                s_bf[1][tk >> 5][d >> 4][((d >> 3) & 1) * 32 + (tk & 31)][d & 7] =
                    (_Float16)(f - (float)fh);
            }
        }
    }
    __syncthreads();

    // ---- B fragments from LDS ----
    v8h bh[2][4], bl[2][4];
    #pragma unroll
    for (int ct = 0; ct < 2; ++ct)
        #pragma unroll
        for (int kc = 0; kc < 4; ++kc) {
            bh[ct][kc] = *(const v8h*)&s_bf[0][ct][kc][lane][0];
            bl[ct][kc] = *(const v8h*)&s_bf[1][ct][kc][lane][0];
        }

    // B5: ones at k=0,1 (pairs with esq chunk)
    v8h b5;
    #pragma unroll
    for (int j = 0; j < 8; ++j) b5[j] = (_Float16)0.0f;
    if (lh == 0) { b5[0] = (_Float16)1.0f; b5[1] = (_Float16)1.0f; }

    v16f Z = {0,0,0,0,0,0,0,0,0,0,0,0,0,0,0,0};
    const float INF = __builtin_huge_valf();
    float bv0 = INF, b20 = INF, bv1 = INF, b21 = INF;
    int   sl0 = 0, sl1 = 0;

    const v8h* Abase = (const v8h*)CH + lane;

    // ---- hot loop: 8 tiles x 26 MFMA (esq + 4kc x {hh, hl, lh}) ----
    #pragma unroll 2
    for (int t = 0; t < 8; ++t) {
        const v8h* Ap = Abase + (size_t)((q * 8 + t) * 9) * 64;
        const v8h ah0 = Ap[0],   ah1 = Ap[64],  ah2 = Ap[128], ah3 = Ap[192];
        const v8h al0 = Ap[256], al1 = Ap[320], al2 = Ap[384], al3 = Ap[448];
        const v8h ae  = Ap[512];

        v16f acc0 = __builtin_amdgcn_mfma_f32_32x32x16_f16(ae, b5, Z, 0, 0, 0);
        v16f acc1 = __builtin_amdgcn_mfma_f32_32x32x16_f16(ae, b5, Z, 0, 0, 0);

        acc0 = __builtin_amdgcn_mfma_f32_32x32x16_f16(ah0, bh[0][0], acc0, 0, 0, 0);
        acc1 = __builtin_amdgcn_mfma_f32_32x32x16_f16(ah0, bh[1][0], acc1, 0, 0, 0);
        acc0 = __builtin_amdgcn_mfma_f32_32x32x16_f16(ah1, bh[0][1], acc0, 0, 0, 0);
        acc1 = __builtin_amdgcn_mfma_f32_32x32x16_f16(ah1, bh[1][1], acc1, 0, 0, 0);
        acc0 = __builtin_amdgcn_mfma_f32_32x32x16_f16(ah2, bh[0][2], acc0, 0, 0, 0);
        acc1 = __builtin_amdgcn_mfma_f32_32x32x16_f16(ah2, bh[1][2], acc1, 0, 0, 0);
        acc0 = __builtin_amdgcn_mfma_f32_32x32x16_f16(ah3, bh[0][3], acc0, 0, 0, 0);
        acc1 = __builtin_amdgcn_mfma_f32_32x32x16_f16(ah3, bh[1][3], acc1, 0, 0, 0);

        acc0 = __builtin_amdgcn_mfma_f32_32x32x16_f16(ah0, bl[0][0], acc0, 0, 0, 0);
        acc1 = __builtin_amdgcn_mfma_f32_32x32x16_f16(ah0, bl[1][0], acc1, 0, 0, 0);
        acc0 = __builtin_amdgcn_mfma_f32_32x32x16_f16(ah1, bl[0][1], acc0, 0, 0, 0);
        acc1 = __builtin_amdgcn_mfma_f32_32x32x16_f16(ah1, bl[1][1], acc1, 0, 0, 0);
        acc0 = __builtin_amdgcn_mfma_f32_32x32x16_f16(ah2, bl[0][2], acc0, 0, 0, 0);
        acc1 = __builtin_amdgcn_mfma_f32_32x32x16_f16(ah2, bl[1][2], acc1, 0, 0, 0);
        acc0 = __builtin_amdgcn_mfma_f32_32x32x16_f16(ah3, bl[0][3], acc0, 0, 0, 0);
        acc1 = __builtin_amdgcn_mfma_f32_32x32x16_f16(ah3, bl[1][3], acc1, 0, 0, 0);

        acc0 = __builtin_amdgcn_mfma_f32_32x32x16_f16(al0, bh[0][0], acc0, 0, 0, 0);
        acc1 = __builtin_amdgcn_mfma_f32_32x32x16_f16(al0, bh[1][0], acc1, 0, 0, 0);
        acc0 = __builtin_amdgcn_mfma_f32_32x32x16_f16(al1, bh[0][1], acc0, 0, 0, 0);
        acc1 = __builtin_amdgcn_mfma_f32_32x32x16_f16(al1, bh[1][1], acc1, 0, 0, 0);
        acc0 = __builtin_amdgcn_mfma_f32_32x32x16_f16(al2, bh[0][2], acc0, 0, 0, 0);
        acc1 = __builtin_amdgcn_mfma_f32_32x32x16_f16(al2, bh[1][2], acc1, 0, 0, 0);
        acc0 = __builtin_amdgcn_mfma_f32_32x32x16_f16(al3, bh[0][3], acc0, 0, 0, 0);
        acc1 = __builtin_amdgcn_mfma_f32_32x32x16_f16(al3, bh[1][3], acc1, 0, 0, 0);

        // track top-2 value + slot (value & slot separate: exact gap test)
        #pragma unroll
        for (int r = 0; r < 16; ++r) {
            const int slot = (t << 4) | r;
            const float s0 = acc0[r];
            b20 = __builtin_amdgcn_fmed3f(s0, bv0, b20);
            if (s0 < bv0) { bv0 = s0; sl0 = slot; }
            const float s1 = acc1[r];
            b21 = __builtin_amdgcn_fmed3f(s1, bv1, b21);
            if (s1 < bv1) { bv1 = s1; sl1 = slot; }
        }
    }

    // ---- cross-half-row merge (lane <-> lane^32), decode cw ----
    #pragma unroll
    for (int ct = 0; ct < 2; ++ct) {
        const float bv = ct ? bv1 : bv0;
        const float b2 = ct ? b21 : b20;
        const int   sl = ct ? sl1 : sl0;
        const float obv = __shfl_xor(bv, 32, 64);
        const float ob2 = __shfl_xor(b2, 32, 64);
        const int   osl = __shfl_xor(sl, 32, 64);
        const bool  oth = obv < bv;            // strict: ties keep own; exact ties flagged
        const float B1  = oth ? obv : bv;
        const float B2  = fminf(fmaxf(bv, obv), fminf(b2, ob2));
        const int   wsl = oth ? osl : sl;
        const int   wlh = oth ? (lh ^ 1) : lh;
        const int   r   = wsl & 15;
        const int   tt  = wsl >> 4;
        const int   cw  = (q * 8 + tt) * 32 + (r & 3) + 8 * (r >> 2) + 4 * wlh;
        if (lane < 32) {
            s_pv[q][ct * 32 + lane] = B1;
            s_p2[q][ct * 32 + lane] = B2;
            s_pk[q][ct * 32 + lane] = cw;
        }
    }
    __syncthreads();

    // ---- merge 4 quarters per token; flag near-ties into list ----
    if (tid < 64) {
        float B1 = INF, B2 = INF; int CW = 0;
        #pragma unroll
        for (int qq = 0; qq < 4; ++qq) {
            const float pv = s_pv[qq][tid];
            const float p2 = s_p2[qq][tid];
            const int   pk = s_pk[qq][tid];
            if (pv < B1) { B2 = fminf(B1, p2); B1 = pv; CW = pk; }
            else         { B2 = fminf(B2, pv); }
        }
        s_idx[tid] = CW;
        if (B2 - B1 < EPS) {
            const int p = atomicAdd(&s_cnt, 1);
            s_list[p] = tid;
        }
    }
    __syncthreads();

    // ---- exact fp32 rescan, BLOCK-cooperative (rare: ~1e-4 of tokens) ----
    {
        const int cnt = s_cnt;
        const int rr  = tid >> 2;   // codeword row within 64-chunk
        const int c   = tid & 3;    // d-quarter
        for (int ii = 0; ii < cnt; ++ii) {
            const int tl = s_list[ii];
            if (tid < 64) s_xf[tid] = input[(size_t)b * DHW + (size_t)tid * HW + (hwb + tl)];
            __syncthreads();
            const float4* xs4 = (const float4*)&s_xf[c * 16];
            const float4 x0 = xs4[0], x1 = xs4[1], x2 = xs4[2], x3 = xs4[3];
            float bestv = INF; int bestk = K;
            #pragma unroll 4
            for (int i = 0; i < 16; ++i) {
                const int k = i * 64 + rr;                     // ascending per thread
                const float4* c4 = (const float4*)(codebook + (size_t)k * D + c * 16);
                const float4 c0 = c4[0], c1 = c4[1], c2 = c4[2], c3 = c4[3];
                float p0 = 0.f, p1 = 0.f, p2 = 0.f, p3 = 0.f;
                p0 = fmaf(x0.x, c0.x, p0); p0 = fmaf(x0.y, c0.y, p0);
                p0 = fmaf(x0.z, c0.z, p0); p0 = fmaf(x0.w, c0.w, p0);
                p1 = fmaf(x1.x, c1.x, p1); p1 = fmaf(x1.y, c1.y, p1);
                p1 = fmaf(x1.z, c1.z, p1); p1 = fmaf(x1.w, c1.w, p1);
                p2 = fmaf(x2.x, c2.x, p2); p2 = fmaf(x2.y, c2.y, p2);
                p2 = fmaf(x2.z, c2.z, p2); p2 = fmaf(x2.w, c2.w, p2);
                p3 = fmaf(x3.x, c3.x, p3); p3 = fmaf(x3.y, c3.y, p3);
                p3 = fmaf(x3.z, c3.z, p3); p3 = fmaf(x3.w, c3.w, p3);
                float dp = (p0 + p1) + (p2 + p3);
                dp += __shfl_xor(dp, 1, 64);                   // sum over d-quarters
                dp += __shfl_xor(dp, 2, 64);
                const float s = fmaf(-2.0f, dp, s_esq[k]);
                if (s < bestv) { bestv = s; bestk = k; }
            }
            #pragma unroll
            for (int off = 4; off <= 32; off <<= 1) {          // reduce over rows in wave
                const float ov = __shfl_xor(bestv, off, 64);
                const int   ok = __shfl_xor(bestk, off, 64);
                if (ov < bestv || (ov == bestv && ok < bestk)) { bestv = ov; bestk = ok; }
            }
            if (lane == 0) { s_redv[q] = bestv; s_redk[q] = bestk; }
            __syncthreads();
            if (tid == 0) {
                float bb = s_redv[0]; int bk = s_redk[0];
                #pragma unroll
                for (int w = 1; w < 4; ++w) {
                    const float v = s_redv[w]; const int kk = s_redk[w];
                    if (v < bb || (v == bb && kk < bk)) { bb = v; bk = kk; }
                }
                s_idx[tl] = bk;
            }
            __syncthreads();
        }
    }

    // ---- epilogue: gather winner rows to LDS, then float4 stores ----
    {
        const int rs  = tid >> 2;
        const int c   = tid & 3;
        const int idx = s_idx[rs];
        const float4* src = (const float4*)(codebook + (size_t)idx * D + c * 16);
        #pragma unroll
        for (int j = 0; j < 4; ++j) {
            const float4 v = src[j];
            float* dst = &s_q[rs][c * 16 + j * 4];
            dst[0] = v.x; dst[1] = v.y; dst[2] = v.z; dst[3] = v.w;
        }
    }
    __syncthreads();
    {
        float* ob = out + (size_t)b * DHW + hwb;
        #pragma unroll
        for (int pass = 0; pass < 4; ++pass) {
            const int d   = pass * 16 + (tid >> 4);
            const int hw4 = (tid & 15) * 4;
            float4 v;
            v.x = s_q[hw4 + 0][d];
            v.y = s_q[hw4 + 1][d];
            v.z = s_q[hw4 + 2][d];
            v.w = s_q[hw4 + 3][d];
            *(float4*)(ob + (size_t)d * HW + hw4) = v;
        }
        if (tid < 64) out[OUT_ELEMS + tok0 + tid] = (float)s_idx[tid];
    }
}

extern "C" void kernel_launch(void* const* d_in, const int* in_sizes, int n_in,
                              void* d_out, int out_size, void* d_ws, size_t ws_size,
                              hipStream_t stream) {
    const float* input    = (const float*)d_in[0];
    const float* codebook = (const float*)d_in[1];
    float* out            = (float*)d_out;

    _Float16* CH  = (_Float16*)d_ws;                   // 294912 B
    float*    esq = (float*)((char*)d_ws + 294912);    // 4096 B

    vq_prep<<<76, 256, 0, stream>>>(codebook, CH, esq);
    vq_scan<<<1024, 256, 0, stream>>>(input, codebook, CH, esq, out);
}

// Round 10
// 104.679 us; speedup vs baseline: 1.7769x; 1.0085x over previous
//
#include <hip/hip_runtime.h>

// VectorQuantizer R13 = R12/R6 + s_q/s_bf LDS union ONLY: input (16,64,64,64) f32,
// codebook (1024,64) f32. out = [quantized | indices-as-f32].
//
// R12 reproduced the baseline (105.6us, scan 47us, occ 18.6%, LDS 41.5K -> 3
// blocks/CU vs grid 4/CU: a 2-round residency tail, wall ~= 2x T_block).
// R13 tests residency CLEAN: union s_q (epilogue-only) with s_bf (staging-only)
// -> LDS ~24.5K -> 6 blocks/CU possible, full grid resident. Union proven
// correct in R7/R8 (absmax 0). NO other change: launch_bounds stays (256,3)
// (R7's (256,4) capped VGPR=64 -> spills), bh+bl stay in registers (R7's
// per-tile bl LDS reads -> +75% conflicts). VGPR should stay 76.
//
// A = codebook, B = tokens, mfma_f32_32x32x16_f16, SPLIT-F16 3-pass:
//   dot = hi*hi + hi*lo + lo*hi (lo*lo ~2^-22 dropped) -> err ~3e-5.
//   esq folded via hi/lo 5th-chunk vs ones-B. EPS=1e-3, exact gap test,
//   block-cooperative exact fp32 rescan, ascending-k ties.

typedef _Float16 v8h  __attribute__((ext_vector_type(8)));
typedef float    v16f __attribute__((ext_vector_type(16)));

constexpr int   D         = 64;
constexpr int   K         = 1024;
constexpr int   HW        = 4096;
constexpr int   DHW       = D * HW;
constexpr int   OUT_ELEMS = 16 * DHW;
constexpr float EPS       = 1e-3f;

// CH: 32 tiles x 9 chunks x 64 lanes x 8 f16 = 288 KB.
// frag f = t*9+kc; CH[f*512 + lane*8 + j]:
//   kc 0-3: hi of -2*C[row = t*32+(lane&31)][k = kc*16+(lane>>5)*8+j]
//   kc 4-7: lo of same
//   kc 8  : lh==0: j0=e_hi, j1=e_lo (pairs with B5 = ones at k=0,1)

__global__ __launch_bounds__(256) void vq_prep(
    const float* __restrict__ cb, _Float16* __restrict__ CH, float* __restrict__ esq)
{
    const int blk = blockIdx.x, tid = threadIdx.x;
    if (blk < 72) {
        const int gid  = blk * 256 + tid;          // [0, 18432)
        const int lane = gid & 63;
        const int fid  = gid >> 6;                 // [0, 288)
        const int t    = fid / 9;
        const int kc   = fid - 9 * t;
        const int l31  = lane & 31;
        const int lh   = lane >> 5;
        const int cw   = t * 32 + l31;
        v8h h;
        if (kc < 8) {
            const int  kk = kc & 3;
            const bool lo = kc >= 4;
            const float* src = cb + cw * D + kk * 16 + lh * 8;
            #pragma unroll
            for (int j = 0; j < 8; ++j) {
                const float v = -2.0f * src[j];
                const _Float16 vh = (_Float16)v;
                h[j] = lo ? (_Float16)(v - (float)vh) : vh;
            }
        } else {
            #pragma unroll
            for (int j = 0; j < 8; ++j) h[j] = (_Float16)0.0f;
            if (lh == 0) {
                const float4* c4 = (const float4*)(cb + cw * D);
                float a0 = 0.f, a1 = 0.f, a2 = 0.f, a3 = 0.f;
                #pragma unroll
                for (int j = 0; j < 16; ++j) {
                    const float4 c = c4[j];
                    a0 = fmaf(c.x, c.x, a0);
                    a1 = fmaf(c.y, c.y, a1);
                    a2 = fmaf(c.z, c.z, a2);
                    a3 = fmaf(c.w, c.w, a3);
                }
                const float e = (a0 + a1) + (a2 + a3);
                const _Float16 ehi = (_Float16)e;
                h[0] = ehi;
                h[1] = (_Float16)(e - (float)ehi);
            }
        }
        *(v8h*)(CH + (size_t)fid * 512 + lane * 8) = h;
    } else {
        const int cw = (blk - 72) * 256 + tid;     // exact f32 e_sq for rescan
        const float4* c4 = (const float4*)(cb + cw * D);
        float a0 = 0.f, a1 = 0.f, a2 = 0.f, a3 = 0.f;
        #pragma unroll
        for (int j = 0; j < 16; ++j) {
            const float4 c = c4[j];
            a0 = fmaf(c.x, c.x, a0);
            a1 = fmaf(c.y, c.y, a1);
            a2 = fmaf(c.z, c.z, a2);
            a3 = fmaf(c.w, c.w, a3);
        }
        esq[cw] = (a0 + a1) + (a2 + a3);
    }
}

__global__ __launch_bounds__(256, 3) void vq_scan(
    const float* __restrict__ input,
    const float* __restrict__ codebook,
    const _Float16* __restrict__ CH,
    const float* __restrict__ esq,
    float* __restrict__ out)
{
    // s_bf (staging, dead after fragment loads) unions s_q (epilogue gather,
    // first written after the rescan barrier). Only change vs R12.
    __shared__ union {
        _Float16 bf[2][2][4][64][8];   // [hi/lo][ct][kc][lane][8], 16 KB
        float    q[64][65];            // winner rows for epilogue, 16.6 KB
    } u;
    __shared__ float    s_esq[K];              // exact e_sq (rescan), 4 KB
    __shared__ float    s_pv[4][64];
    __shared__ float    s_p2[4][64];
    __shared__ int      s_pk[4][64];
    __shared__ int      s_idx[64];
    __shared__ int      s_list[64];
    __shared__ int      s_cnt;
    __shared__ float    s_xf[64];              // rescan token (f32)
    __shared__ float    s_redv[4];
    __shared__ int      s_redk[4];

    const int tid  = threadIdx.x;
    const int lane = tid & 63;
    const int q    = __builtin_amdgcn_readfirstlane(tid >> 6);  // K-quarter
    const int lh   = lane >> 5;
    const int tok0 = blockIdx.x * 64;
    const int b    = tok0 >> 12;
    const int hwb  = tok0 & 4095;

    if (tid == 0) s_cnt = 0;

    // ---- stage exact e_sq ----
    *(float4*)&s_esq[tid * 4] = *(const float4*)&esq[tid * 4];

    // ---- cooperative B staging: hi+lo split ----
    {
        const float* xb = input + (size_t)b * DHW + hwb;
        #pragma unroll
        for (int pass = 0; pass < 4; ++pass) {
            const int d   = pass * 16 + (tid >> 4);
            const int hw4 = (tid & 15) * 4;
            const float4 v = *(const float4*)(xb + (size_t)d * HW + hw4);
            const float vv[4] = {v.x, v.y, v.z, v.w};
            #pragma unroll
            for (int uu = 0; uu < 4; ++uu) {
                const int tk = hw4 + uu;
                const float f = vv[uu];
                const _Float16 fh = (_Float16)f;
                u.bf[0][tk >> 5][d >> 4][((d >> 3) & 1) * 32 + (tk & 31)][d & 7] = fh;
                u.bf[1][tk >> 5][d >> 4][((d >> 3) & 1) * 32 + (tk & 31)][d & 7] =
                    (_Float16)(f - (float)fh);
            }
        }
    }
    __syncthreads();

    // ---- B fragments from LDS ----
    v8h bh[2][4], bl[2][4];
    #pragma unroll
    for (int ct = 0; ct < 2; ++ct)
        #pragma unroll
        for (int kc = 0; kc < 4; ++kc) {
            bh[ct][kc] = *(const v8h*)&u.bf[0][ct][kc][lane][0];
            bl[ct][kc] = *(const v8h*)&u.bf[1][ct][kc][lane][0];
        }

    // B5: ones at k=0,1 (pairs with esq chunk)
    v8h b5;
    #pragma unroll
    for (int j = 0; j < 8; ++j) b5[j] = (_Float16)0.0f;
    if (lh == 0) { b5[0] = (_Float16)1.0f; b5[1] = (_Float16)1.0f; }

    v16f Z = {0,0,0,0,0,0,0,0,0,0,0,0,0,0,0,0};
    const float INF = __builtin_huge_valf();
    float bv0 = INF, b20 = INF, bv1 = INF, b21 = INF;
    int   sl0 = 0, sl1 = 0;

    const v8h* Abase = (const v8h*)CH + lane;

    // ---- hot loop: 8 tiles x 26 MFMA (esq + 4kc x {hh, hl, lh}) ----
    #pragma unroll 2
    for (int t = 0; t < 8; ++t) {
        const v8h* Ap = Abase + (size_t)((q * 8 + t) * 9) * 64;
        const v8h ah0 = Ap[0],   ah1 = Ap[64],  ah2 = Ap[128], ah3 = Ap[192];
        const v8h al0 = Ap[256], al1 = Ap[320], al2 = Ap[384], al3 = Ap[448];
        const v8h ae  = Ap[512];

        v16f acc0 = __builtin_amdgcn_mfma_f32_32x32x16_f16(ae, b5, Z, 0, 0, 0);
        v16f acc1 = __builtin_amdgcn_mfma_f32_32x32x16_f16(ae, b5, Z, 0, 0, 0);

        acc0 = __builtin_amdgcn_mfma_f32_32x32x16_f16(ah0, bh[0][0], acc0, 0, 0, 0);
        acc1 = __builtin_amdgcn_mfma_f32_32x32x16_f16(ah0, bh[1][0], acc1, 0, 0, 0);
        acc0 = __builtin_amdgcn_mfma_f32_32x32x16_f16(ah1, bh[0][1], acc0, 0, 0, 0);
        acc1 = __builtin_amdgcn_mfma_f32_32x32x16_f16(ah1, bh[1][1], acc1, 0, 0, 0);
        acc0 = __builtin_amdgcn_mfma_f32_32x32x16_f16(ah2, bh[0][2], acc0, 0, 0, 0);
        acc1 = __builtin_amdgcn_mfma_f32_32x32x16_f16(ah2, bh[1][2], acc1, 0, 0, 0);
        acc0 = __builtin_amdgcn_mfma_f32_32x32x16_f16(ah3, bh[0][3], acc0, 0, 0, 0);
        acc1 = __builtin_amdgcn_mfma_f32_32x32x16_f16(ah3, bh[1][3], acc1, 0, 0, 0);

        acc0 = __builtin_amdgcn_mfma_f32_32x32x16_f16(ah0, bl[0][0], acc0, 0, 0, 0);
        acc1 = __builtin_amdgcn_mfma_f32_32x32x16_f16(ah0, bl[1][0], acc1, 0, 0, 0);
        acc0 = __builtin_amdgcn_mfma_f32_32x32x16_f16(ah1, bl[0][1], acc0, 0, 0, 0);
        acc1 = __builtin_amdgcn_mfma_f32_32x32x16_f16(ah1, bl[1][1], acc1, 0, 0, 0);
        acc0 = __builtin_amdgcn_mfma_f32_32x32x16_f16(ah2, bl[0][2], acc0, 0, 0, 0);
        acc1 = __builtin_amdgcn_mfma_f32_32x32x16_f16(ah2, bl[1][2], acc1, 0, 0, 0);
        acc0 = __builtin_amdgcn_mfma_f32_32x32x16_f16(ah3, bl[0][3], acc0, 0, 0, 0);
        acc1 = __builtin_amdgcn_mfma_f32_32x32x16_f16(ah3, bl[1][3], acc1, 0, 0, 0);

        acc0 = __builtin_amdgcn_mfma_f32_32x32x16_f16(al0, bh[0][0], acc0, 0, 0, 0);
        acc1 = __builtin_amdgcn_mfma_f32_32x32x16_f16(al0, bh[1][0], acc1, 0, 0, 0);
        acc0 = __builtin_amdgcn_mfma_f32_32x32x16_f16(al1, bh[0][1], acc0, 0, 0, 0);
        acc1 = __builtin_amdgcn_mfma_f32_32x32x16_f16(al1, bh[1][1], acc1, 0, 0, 0);
        acc0 = __builtin_amdgcn_mfma_f32_32x32x16_f16(al2, bh[0][2], acc0, 0, 0, 0);
        acc1 = __builtin_amdgcn_mfma_f32_32x32x16_f16(al2, bh[1][2], acc1, 0, 0, 0);
        acc0 = __builtin_amdgcn_mfma_f32_32x32x16_f16(al3, bh[0][3], acc0, 0, 0, 0);
        acc1 = __builtin_amdgcn_mfma_f32_32x32x16_f16(al3, bh[1][3], acc1, 0, 0, 0);

        // track top-2 value + slot (value & slot separate: exact gap test)
        #pragma unroll
        for (int r = 0; r < 16; ++r) {
            const int slot = (t << 4) | r;
            const float s0 = acc0[r];
            b20 = __builtin_amdgcn_fmed3f(s0, bv0, b20);
            if (s0 < bv0) { bv0 = s0; sl0 = slot; }
            const float s1 = acc1[r];
            b21 = __builtin_amdgcn_fmed3f(s1, bv1, b21);
            if (s1 < bv1) { bv1 = s1; sl1 = slot; }
        }
    }

    // ---- cross-half-row merge (lane <-> lane^32), decode cw ----
    #pragma unroll
    for (int ct = 0; ct < 2; ++ct) {
        const float bv = ct ? bv1 : bv0;
        const float b2 = ct ? b21 : b20;
        const int   sl = ct ? sl1 : sl0;
        const float obv = __shfl_xor(bv, 32, 64);
        const float ob2 = __shfl_xor(b2, 32, 64);
        const int   osl = __shfl_xor(sl, 32, 64);
        const bool  oth = obv < bv;            // strict: ties keep own; exact ties flagged
        const float B1  = oth ? obv : bv;
        const float B2  = fminf(fmaxf(bv, obv), fminf(b2, ob2));
        const int   wsl = oth ? osl : sl;
        const int   wlh = oth ? (lh ^ 1) : lh;
        const int   r   = wsl & 15;
        const int   tt  = wsl >> 4;
        const int   cw  = (q * 8 + tt) * 32 + (r & 3) + 8 * (r >> 2) + 4 * wlh;
        if (lane < 32) {
            s_pv[q][ct * 32 + lane] = B1;
            s_p2[q][ct * 32 + lane] = B2;
            s_pk[q][ct * 32 + lane] = cw;
        }
    }
    __syncthreads();

    // ---- merge 4 quarters per token; flag near-ties into list ----
    if (tid < 64) {
        float B1 = INF, B2 = INF; int CW = 0;
        #pragma unroll
        for (int qq = 0; qq < 4; ++qq) {
            const float pv = s_pv[qq][tid];
            const float p2 = s_p2[qq][tid];
            const int   pk = s_pk[qq][tid];
            if (pv < B1) { B2 = fminf(B1, p2); B1 = pv; CW = pk; }
            else         { B2 = fminf(B2, pv); }
        }
        s_idx[tid] = CW;
        if (B2 - B1 < EPS) {
            const int p = atomicAdd(&s_cnt, 1);
            s_list[p] = tid;
        }
    }
    __syncthreads();

    // ---- exact fp32 rescan, BLOCK-cooperative (rare: ~1e-4 of tokens) ----
    {
        const int cnt = s_cnt;
        const int rr  = tid >> 2;   // codeword row within 64-chunk
        const int c   = tid & 3;    // d-quarter
        for (int ii = 0; ii < cnt; ++ii) {
            const int tl = s_list[ii];
            if (tid < 64) s_xf[tid] = input[(size_t)b * DHW + (size_t)tid * HW + (hwb + tl)];
            __syncthreads();
            const float4* xs4 = (const float4*)&s_xf[c * 16];
            const float4 x0 = xs4[0], x1 = xs4[1], x2 = xs4[2], x3 = xs4[3];
            float bestv = INF; int bestk = K;
            #pragma unroll 4
            for (int i = 0; i < 16; ++i) {
                const int k = i * 64 + rr;                     // ascending per thread
                const float4* c4 = (const float4*)(codebook + (size_t)k * D + c * 16);
                const float4 c0 = c4[0], c1 = c4[1], c2 = c4[2], c3 = c4[3];
                float p0 = 0.f, p1 = 0.f, p2 = 0.f, p3 = 0.f;
                p0 = fmaf(x0.x, c0.x, p0); p0 = fmaf(x0.y, c0.y, p0);
                p0 = fmaf(x0.z, c0.z, p0); p0 = fmaf(x0.w, c0.w, p0);
                p1 = fmaf(x1.x, c1.x, p1); p1 = fmaf(x1.y, c1.y, p1);
                p1 = fmaf(x1.z, c1.z, p1); p1 = fmaf(x1.w, c1.w, p1);
                p2 = fmaf(x2.x, c2.x, p2); p2 = fmaf(x2.y, c2.y, p2);
                p2 = fmaf(x2.z, c2.z, p2); p2 = fmaf(x2.w, c2.w, p2);
                p3 = fmaf(x3.x, c3.x, p3); p3 = fmaf(x3.y, c3.y, p3);
                p3 = fmaf(x3.z, c3.z, p3); p3 = fmaf(x3.w, c3.w, p3);
                float dp = (p0 + p1) + (p2 + p3);
                dp += __shfl_xor(dp, 1, 64);                   // sum over d-quarters
                dp += __shfl_xor(dp, 2, 64);
                const float s = fmaf(-2.0f, dp, s_esq[k]);
                if (s < bestv) { bestv = s; bestk = k; }
            }
            #pragma unroll
            for (int off = 4; off <= 32; off <<= 1) {          // reduce over rows in wave
                const float ov = __shfl_xor(bestv, off, 64);
                const int   ok = __shfl_xor(bestk, off, 64);
                if (ov < bestv || (ov == bestv && ok < bestk)) { bestv = ov; bestk = ok; }
            }
            if (lane == 0) { s_redv[q] = bestv; s_redk[q] = bestk; }
            __syncthreads();
            if (tid == 0) {
                float bb = s_redv[0]; int bk = s_redk[0];
                #pragma unroll
                for (int w = 1; w < 4; ++w) {
                    const float v = s_redv[w]; const int kk = s_redk[w];
                    if (v < bb || (v == bb && kk < bk)) { bb = v; bk = kk; }
                }
                s_idx[tl] = bk;
            }
            __syncthreads();
        }
    }

    // ---- epilogue: gather winner rows to LDS (u.q overlays dead u.bf) ----
    {
        const int rs  = tid >> 2;
        const int c   = tid & 3;
        const int idx = s_idx[rs];
        const float4* src = (const float4*)(codebook + (size_t)idx * D + c * 16);
        #pragma unroll
        for (int j = 0; j < 4; ++j) {
            const float4 v = src[j];
            float* dst = &u.q[rs][c * 16 + j * 4];
            dst[0] = v.x; dst[1] = v.y; dst[2] = v.z; dst[3] = v.w;
        }
    }
    __syncthreads();
    {
        float* ob = out + (size_t)b * DHW + hwb;
        #pragma unroll
        for (int pass = 0; pass < 4; ++pass) {
            const int d   = pass * 16 + (tid >> 4);
            const int hw4 = (tid & 15) * 4;
            float4 v;
            v.x = u.q[hw4 + 0][d];
            v.y = u.q[hw4 + 1][d];
            v.z = u.q[hw4 + 2][d];
            v.w = u.q[hw4 + 3][d];
            *(float4*)(ob + (size_t)d * HW + hw4) = v;
        }
        if (tid < 64) out[OUT_ELEMS + tok0 + tid] = (float)s_idx[tid];
    }
}

extern "C" void kernel_launch(void* const* d_in, const int* in_sizes, int n_in,
                              void* d_out, int out_size, void* d_ws, size_t ws_size,
                              hipStream_t stream) {
    const float* input    = (const float*)d_in[0];
    const float* codebook = (const float*)d_in[1];
    float* out            = (float*)d_out;

    _Float16* CH  = (_Float16*)d_ws;                   // 294912 B
    float*    esq = (float*)((char*)d_ws + 294912);    // 4096 B

    vq_prep<<<76, 256, 0, stream>>>(codebook, CH, esq);
    vq_scan<<<1024, 256, 0, stream>>>(input, codebook, CH, esq, out);
}